// Round 4
// baseline (66.971 us; speedup 1.0000x reference)
//
#include <hip/hip_runtime.h>
#include <math.h>

namespace {
constexpr int kB  = 2048;
constexpr int kSW = 2048;     // short width
constexpr int kLW = 8192;     // long width
constexpr int kLP = kLW / 2;  // pooled length = 4096
constexpr int kROWS = 4;      // batch rows per block
constexpr int kLBLKS = (kB / kROWS) * 2;  // 1024: long, 2 position-halves
constexpr int kSBLKS = (kB / kROWS) * 2;  // 1024: short, 2 position-halves
}

// force a wave-uniform float into an SGPR
__device__ __forceinline__ float rfl(float x) {
  return __uint_as_float(__builtin_amdgcn_readfirstlane(__float_as_uint(x)));
}

// ------------- long branch half: conv(k=5,p=2) -> relu -> maxpool(2) -> partial dot -------------
__device__ __forceinline__ void long_half(
    int blk, int h, const float* __restrict__ xl, const float* __restrict__ cw,
    const float* __restrict__ cb, const float* __restrict__ lw,
    float* __restrict__ part) {
  __shared__ float red[kROWS][2][4];
  const int tid = threadIdx.x;
  const int b0 = blk * kROWS;

  float wgt[8][5], bias[8];   // SGPR-resident (wave-uniform)
#pragma unroll
  for (int c = 0; c < 8; ++c) {
#pragma unroll
    for (int k = 0; k < 5; ++k) wgt[c][k] = rfl(cw[c * 5 + k]);
    bias[c] = rfl(cb[c]);
  }

  float acc[kROWS][2];
#pragma unroll
  for (int r = 0; r < kROWS; ++r) { acc[r][0] = 0.f; acc[r][1] = 0.f; }

  for (int ch = 0; ch < 2; ++ch) {
    const int p0 = h * 2048 + ch * 1024 + tid * 4;  // pooled base (mult of 4)
    const int s  = 2 * p0;                          // conv-input base (mult of 8)

    // window w[r][0..11] = x[s-2 .. s+9] (zero-padded at edges)
    float w[kROWS][12];
#pragma unroll
    for (int r = 0; r < kROWS; ++r) {
      const float* x = xl + (size_t)(b0 + r) * kLW;
      float2 hm = (p0 > 0) ? *reinterpret_cast<const float2*>(x + s - 2)
                           : make_float2(0.f, 0.f);
      float4 f0 = *reinterpret_cast<const float4*>(x + s);
      float4 f1 = *reinterpret_cast<const float4*>(x + s + 4);
      float2 f2 = (s + 8 < kLW) ? *reinterpret_cast<const float2*>(x + s + 8)
                                : make_float2(0.f, 0.f);
      w[r][0] = hm.x; w[r][1] = hm.y;
      w[r][2] = f0.x; w[r][3] = f0.y; w[r][4] = f0.z; w[r][5] = f0.w;
      w[r][6] = f1.x; w[r][7] = f1.y; w[r][8] = f1.z; w[r][9] = f1.w;
      w[r][10] = f2.x; w[r][11] = f2.y;
    }

#pragma unroll
    for (int c = 0; c < 8; ++c) {
      float4 la4 = *reinterpret_cast<const float4*>(lw + (size_t)c * kLP + p0);
      float4 lb4 = *reinterpret_cast<const float4*>(lw + (size_t)(8 + c) * kLP + p0);
      const float la[4] = {la4.x, la4.y, la4.z, la4.w};
      const float lbv[4] = {lb4.x, lb4.y, lb4.z, lb4.w};
#pragma unroll
      for (int r = 0; r < kROWS; ++r) {
#pragma unroll
        for (int u = 0; u < 4; ++u) {
          // raw convs (no bias seed -> single-SGPR-operand FMAs)
          float v0 = wgt[c][0] * w[r][2 * u + 0];
          v0 = fmaf(wgt[c][1], w[r][2 * u + 1], v0);
          v0 = fmaf(wgt[c][2], w[r][2 * u + 2], v0);
          v0 = fmaf(wgt[c][3], w[r][2 * u + 3], v0);
          v0 = fmaf(wgt[c][4], w[r][2 * u + 4], v0);
          float v1 = wgt[c][0] * w[r][2 * u + 1];
          v1 = fmaf(wgt[c][1], w[r][2 * u + 2], v1);
          v1 = fmaf(wgt[c][2], w[r][2 * u + 3], v1);
          v1 = fmaf(wgt[c][3], w[r][2 * u + 4], v1);
          v1 = fmaf(wgt[c][4], w[r][2 * u + 5], v1);
          // relu(conv+b) then maxpool == relu(max(raw)+b)  (monotone)
          const float m = fmaxf(fmaxf(v0, v1) + bias[c], 0.f);
          acc[r][0] = fmaf(m, la[u], acc[r][0]);
          acc[r][1] = fmaf(m, lbv[u], acc[r][1]);
        }
      }
    }
  }

#pragma unroll
  for (int r = 0; r < kROWS; ++r)
#pragma unroll
    for (int o = 0; o < 2; ++o) {
      float a = acc[r][o];
#pragma unroll
      for (int off = 32; off > 0; off >>= 1) a += __shfl_down(a, off);
      if ((tid & 63) == 0) red[r][o][tid >> 6] = a;
    }
  __syncthreads();
  if (tid < kROWS * 2) {
    const int r = tid >> 1, o = tid & 1;
    part[(size_t)h * kB * 4 + (size_t)(b0 + r) * 4 + 2 + o] =
        red[r][o][0] + red[r][o][1] + red[r][o][2] + red[r][o][3];
  }
}

// ------------- short branch half: conv(k=3,p=1) -> relu -> partial dot -------------
__device__ __forceinline__ void short_half(
    int blk, int h, const float* __restrict__ xs, const float* __restrict__ cw,
    const float* __restrict__ cb, const float* __restrict__ lw,
    float* __restrict__ part) {
  __shared__ float red[kROWS][2][4];
  const int tid = threadIdx.x;
  const int b0 = blk * kROWS;

  float wgt[8][3], bias[8];   // SGPR-resident
#pragma unroll
  for (int c = 0; c < 8; ++c) {
#pragma unroll
    for (int k = 0; k < 3; ++k) wgt[c][k] = rfl(cw[c * 3 + k]);
    bias[c] = rfl(cb[c]);
  }

  float acc[kROWS][2];
#pragma unroll
  for (int r = 0; r < kROWS; ++r) { acc[r][0] = 0.f; acc[r][1] = 0.f; }

  {
    const int p0 = h * 1024 + tid * 4;  // position base (mult of 4)

    float w[kROWS][6];  // x[p0-1 .. p0+4]
#pragma unroll
    for (int r = 0; r < kROWS; ++r) {
      const float* x = xs + (size_t)(b0 + r) * kSW;
      float xm = (p0 > 0) ? x[p0 - 1] : 0.f;
      float4 f0 = *reinterpret_cast<const float4*>(x + p0);
      float xp = (p0 + 4 < kSW) ? x[p0 + 4] : 0.f;
      w[r][0] = xm;
      w[r][1] = f0.x; w[r][2] = f0.y; w[r][3] = f0.z; w[r][4] = f0.w;
      w[r][5] = xp;
    }

#pragma unroll
    for (int c = 0; c < 8; ++c) {
      float4 la4 = *reinterpret_cast<const float4*>(lw + (size_t)c * kSW + p0);
      float4 lb4 = *reinterpret_cast<const float4*>(lw + (size_t)(8 + c) * kSW + p0);
      const float la[4] = {la4.x, la4.y, la4.z, la4.w};
      const float lbv[4] = {lb4.x, lb4.y, lb4.z, lb4.w};
#pragma unroll
      for (int r = 0; r < kROWS; ++r) {
#pragma unroll
        for (int u = 0; u < 4; ++u) {
          float v = wgt[c][0] * w[r][u];
          v = fmaf(wgt[c][1], w[r][u + 1], v);
          v = fmaf(wgt[c][2], w[r][u + 2], v);
          const float m = fmaxf(v + bias[c], 0.f);
          acc[r][0] = fmaf(m, la[u], acc[r][0]);
          acc[r][1] = fmaf(m, lbv[u], acc[r][1]);
        }
      }
    }
  }

#pragma unroll
  for (int r = 0; r < kROWS; ++r)
#pragma unroll
    for (int o = 0; o < 2; ++o) {
      float a = acc[r][o];
#pragma unroll
      for (int off = 32; off > 0; off >>= 1) a += __shfl_down(a, off);
      if ((tid & 63) == 0) red[r][o][tid >> 6] = a;
    }
  __syncthreads();
  if (tid < kROWS * 2) {
    const int r = tid >> 1, o = tid & 1;
    part[(size_t)h * kB * 4 + (size_t)(b0 + r) * 4 + o] =
        red[r][o][0] + red[r][o][1] + red[r][o][2] + red[r][o][3];
  }
}

// ------------- fused feature kernel: long/short interleaved -------------
__global__ __launch_bounds__(256, 4) void features_kernel(
    const float* __restrict__ xs, const float* __restrict__ cs_cw,
    const float* __restrict__ cs_cb, const float* __restrict__ cs_lw,
    const float* __restrict__ xl, const float* __restrict__ cl_cw,
    const float* __restrict__ cl_cb, const float* __restrict__ cl_lw,
    float* __restrict__ part) {
  const int bid = blockIdx.x;
  const int idx = bid >> 1;
  if ((bid & 1) == 0)
    long_half(idx >> 1, idx & 1, xl, cl_cw, cl_cb, cl_lw, part);
  else
    short_half(idx >> 1, idx & 1, xs, cs_cw, cs_cb, cs_lw, part);
}

// ---------------- 4-qubit statevector circuit + final linear ----------------
template <int MASK>
__device__ __forceinline__ void apply_1q(float (&ar)[16], float (&ai)[16],
                                         float u00r, float u00i, float u01r, float u01i,
                                         float u10r, float u10i, float u11r, float u11i) {
#pragma unroll
  for (int i = 0; i < 16; ++i) {
    if (!(i & MASK)) {
      const int j = i | MASK;
      const float a0r = ar[i], a0i = ai[i];
      const float a1r = ar[j], a1i = ai[j];
      ar[i] = u00r * a0r - u00i * a0i + u01r * a1r - u01i * a1i;
      ai[i] = u00r * a0i + u00i * a0r + u01r * a1i + u01i * a1r;
      ar[j] = u10r * a0r - u10i * a0i + u11r * a1r - u11i * a1i;
      ai[j] = u10r * a0i + u10i * a0r + u11r * a1i + u11i * a1r;
    }
  }
}

template <int MASK>
__device__ __forceinline__ void apply_ry(float (&ar)[16], float (&ai)[16], float half_t) {
  float s, c;
  sincosf(half_t, &s, &c);
  apply_1q<MASK>(ar, ai, c, 0.f, -s, 0.f, s, 0.f, c, 0.f);
}

// Rot(phi, theta, omega) = RZ(omega) @ RY(theta) @ RZ(phi)
template <int MASK>
__device__ __forceinline__ void apply_rot(float (&ar)[16], float (&ai)[16],
                                          float phi, float theta, float omega) {
  float st, ct; sincosf(0.5f * theta, &st, &ct);
  float sa, ca; sincosf(0.5f * (phi + omega), &sa, &ca);
  float sm, cm; sincosf(0.5f * (phi - omega), &sm, &cm);
  apply_1q<MASK>(ar, ai,
                 ct * ca, -ct * sa,
                 -st * cm, -st * sm,
                 st * cm, -st * sm,
                 ct * ca, ct * sa);
}

template <int MC, int MT>
__device__ __forceinline__ void apply_cnot(float (&ar)[16], float (&ai)[16]) {
#pragma unroll
  for (int i = 0; i < 16; ++i) {
    if ((i & MC) && !(i & MT)) {
      const int j = i | MT;
      float t;
      t = ar[i]; ar[i] = ar[j]; ar[j] = t;
      t = ai[i]; ai[i] = ai[j]; ai[j] = t;
    }
  }
}

__global__ __launch_bounds__(64) void quantum_kernel(
    const float* __restrict__ part, const float* __restrict__ cs_lb,
    const float* __restrict__ cl_lb, const float* __restrict__ rw,
    const float* __restrict__ fcw, const float* __restrict__ fcb,
    float* __restrict__ out) {
  const int b = blockIdx.x * 64 + threadIdx.x;
  if (b >= kB) return;

  const float f0 = part[(size_t)b * 4 + 0] + part[(size_t)kB * 4 + b * 4 + 0] + cs_lb[0];
  const float f1 = part[(size_t)b * 4 + 1] + part[(size_t)kB * 4 + b * 4 + 1] + cs_lb[1];
  const float f2 = part[(size_t)b * 4 + 2] + part[(size_t)kB * 4 + b * 4 + 2] + cl_lb[0];
  const float f3 = part[(size_t)b * 4 + 3] + part[(size_t)kB * 4 + b * 4 + 3] + cl_lb[1];

  float ar[16], ai[16];
#pragma unroll
  for (int i = 0; i < 16; ++i) { ar[i] = 0.f; ai[i] = 0.f; }
  ar[0] = 1.f;

  const float kHalfPi = 1.57079632679489662f;
  apply_ry<8>(ar, ai, kHalfPi * f0);
  apply_ry<4>(ar, ai, kHalfPi * f1);
  apply_ry<2>(ar, ai, kHalfPi * f2);
  apply_ry<1>(ar, ai, kHalfPi * f3);

  // layer 0, r = 1
  apply_rot<8>(ar, ai, rw[0], rw[1], rw[2]);
  apply_rot<4>(ar, ai, rw[3], rw[4], rw[5]);
  apply_rot<2>(ar, ai, rw[6], rw[7], rw[8]);
  apply_rot<1>(ar, ai, rw[9], rw[10], rw[11]);
  apply_cnot<8, 4>(ar, ai);
  apply_cnot<4, 2>(ar, ai);
  apply_cnot<2, 1>(ar, ai);
  apply_cnot<1, 8>(ar, ai);

  // layer 1, r = 2
  apply_rot<8>(ar, ai, rw[12], rw[13], rw[14]);
  apply_rot<4>(ar, ai, rw[15], rw[16], rw[17]);
  apply_rot<2>(ar, ai, rw[18], rw[19], rw[20]);
  apply_rot<1>(ar, ai, rw[21], rw[22], rw[23]);
  apply_cnot<8, 2>(ar, ai);
  apply_cnot<4, 1>(ar, ai);
  apply_cnot<2, 8>(ar, ai);
  apply_cnot<1, 4>(ar, ai);

  // layer 2, r = 3
  apply_rot<8>(ar, ai, rw[24], rw[25], rw[26]);
  apply_rot<4>(ar, ai, rw[27], rw[28], rw[29]);
  apply_rot<2>(ar, ai, rw[30], rw[31], rw[32]);
  apply_rot<1>(ar, ai, rw[33], rw[34], rw[35]);
  apply_cnot<8, 1>(ar, ai);
  apply_cnot<4, 8>(ar, ai);
  apply_cnot<2, 4>(ar, ai);
  apply_cnot<1, 2>(ar, ai);

  float z0 = 0.f, z1 = 0.f, z2 = 0.f, z3 = 0.f;
#pragma unroll
  for (int i = 0; i < 16; ++i) {
    const float p = ar[i] * ar[i] + ai[i] * ai[i];
    z0 += (i & 8) ? -p : p;
    z1 += (i & 4) ? -p : p;
    z2 += (i & 2) ? -p : p;
    z3 += (i & 1) ? -p : p;
  }
  out[b] = fcb[0] + z0 * fcw[0] + z1 * fcw[1] + z2 * fcw[2] + z3 * fcw[3];
}

extern "C" void kernel_launch(void* const* d_in, const int* in_sizes, int n_in,
                              void* d_out, int out_size, void* d_ws, size_t ws_size,
                              hipStream_t stream) {
  const float* xs     = (const float*)d_in[0];
  const float* xl     = (const float*)d_in[1];
  const float* cs_cw  = (const float*)d_in[2];
  const float* cs_cb  = (const float*)d_in[3];
  const float* cs_lw  = (const float*)d_in[4];
  const float* cs_lb  = (const float*)d_in[5];
  const float* cl_cw  = (const float*)d_in[6];
  const float* cl_cb  = (const float*)d_in[7];
  const float* cl_lw  = (const float*)d_in[8];
  const float* cl_lb  = (const float*)d_in[9];
  const float* rw     = (const float*)d_in[10];
  const float* fcw    = (const float*)d_in[11];
  const float* fcb    = (const float*)d_in[12];
  float* out  = (float*)d_out;
  float* part = (float*)d_ws;  // [2][kB][4] partial features

  hipLaunchKernelGGL(features_kernel, dim3(kLBLKS + kSBLKS), dim3(256), 0, stream,
                     xs, cs_cw, cs_cb, cs_lw,
                     xl, cl_cw, cl_cb, cl_lw, part);
  hipLaunchKernelGGL(quantum_kernel, dim3(kB / 64), dim3(64), 0, stream,
                     part, cs_lb, cl_lb, rw, fcw, fcb, out);
}

// Round 5
// 46.520 us; speedup vs baseline: 1.4396x; 1.4396x over previous
//
#include <hip/hip_runtime.h>
#include <math.h>

namespace {
constexpr int kB  = 2048;
constexpr int kSW = 2048;     // short width
constexpr int kLW = 8192;     // long width
constexpr int kLP = kLW / 2;  // pooled length = 4096
constexpr int kROWS = 4;      // batch rows per block
constexpr int kLBLKS = (kB / kROWS) * 2;  // 1024: long, 2 position-halves
constexpr int kSBLKS = (kB / kROWS) * 2;  // 1024: short, 2 position-halves
}

// ------------- long branch half: conv(k=5,p=2) -> relu -> maxpool(2) -> partial dot -------------
// 4 batch rows / block, half the pooled positions, 4 positions / thread / chunk.
// All VMEM loads for a chunk are issued before the FMA burn (needs ~140 VGPRs).
__device__ __forceinline__ void long_half(
    int blk, int h, const float* __restrict__ xl, const float* __restrict__ cw,
    const float* __restrict__ cb, const float* __restrict__ lw,
    float* __restrict__ part) {
  __shared__ float red[kROWS][2][4];
  const int tid = threadIdx.x;
  const int b0 = blk * kROWS;

  float wgt[8][5], bias[8];
#pragma unroll
  for (int c = 0; c < 8; ++c) {
#pragma unroll
    for (int k = 0; k < 5; ++k) wgt[c][k] = cw[c * 5 + k];
    bias[c] = cb[c];
  }

  float acc[kROWS][2];
#pragma unroll
  for (int r = 0; r < kROWS; ++r) { acc[r][0] = 0.f; acc[r][1] = 0.f; }

  for (int ch = 0; ch < 2; ++ch) {
    const int p0 = h * 2048 + ch * 1024 + tid * 4;  // pooled base (mult of 4)
    const int s  = 2 * p0;                          // conv-input base (mult of 8)

    // ---- issue ALL loads for this chunk first (32 VMEM in flight) ----
    float w[kROWS][12];  // x[s-2 .. s+9], zero-padded at edges
#pragma unroll
    for (int r = 0; r < kROWS; ++r) {
      const float* x = xl + (size_t)(b0 + r) * kLW;
      float2 hm = (p0 > 0) ? *reinterpret_cast<const float2*>(x + s - 2)
                           : make_float2(0.f, 0.f);
      float4 f0 = *reinterpret_cast<const float4*>(x + s);
      float4 f1 = *reinterpret_cast<const float4*>(x + s + 4);
      float2 f2 = (s + 8 < kLW) ? *reinterpret_cast<const float2*>(x + s + 8)
                                : make_float2(0.f, 0.f);
      w[r][0] = hm.x; w[r][1] = hm.y;
      w[r][2] = f0.x; w[r][3] = f0.y; w[r][4] = f0.z; w[r][5] = f0.w;
      w[r][6] = f1.x; w[r][7] = f1.y; w[r][8] = f1.z; w[r][9] = f1.w;
      w[r][10] = f2.x; w[r][11] = f2.y;
    }
    float4 la4[8], lb4[8];  // fully-unrolled static indexing -> registers
#pragma unroll
    for (int c = 0; c < 8; ++c) {
      la4[c] = *reinterpret_cast<const float4*>(lw + (size_t)c * kLP + p0);
      lb4[c] = *reinterpret_cast<const float4*>(lw + (size_t)(8 + c) * kLP + p0);
    }

    // ---- FMA burn ----
#pragma unroll
    for (int c = 0; c < 8; ++c) {
      const float la[4] = {la4[c].x, la4[c].y, la4[c].z, la4[c].w};
      const float lbv[4] = {lb4[c].x, lb4[c].y, lb4[c].z, lb4[c].w};
#pragma unroll
      for (int r = 0; r < kROWS; ++r) {
#pragma unroll
        for (int u = 0; u < 4; ++u) {
          float v0 = fmaf(wgt[c][0], w[r][2 * u + 0],
                     fmaf(wgt[c][1], w[r][2 * u + 1],
                     fmaf(wgt[c][2], w[r][2 * u + 2],
                     fmaf(wgt[c][3], w[r][2 * u + 3],
                     fmaf(wgt[c][4], w[r][2 * u + 4], bias[c])))));
          float v1 = fmaf(wgt[c][0], w[r][2 * u + 1],
                     fmaf(wgt[c][1], w[r][2 * u + 2],
                     fmaf(wgt[c][2], w[r][2 * u + 3],
                     fmaf(wgt[c][3], w[r][2 * u + 4],
                     fmaf(wgt[c][4], w[r][2 * u + 5], bias[c])))));
          const float m = fmaxf(fmaxf(v0, v1), 0.f);
          acc[r][0] = fmaf(m, la[u], acc[r][0]);
          acc[r][1] = fmaf(m, lbv[u], acc[r][1]);
        }
      }
    }
  }

#pragma unroll
  for (int r = 0; r < kROWS; ++r)
#pragma unroll
    for (int o = 0; o < 2; ++o) {
      float a = acc[r][o];
#pragma unroll
      for (int off = 32; off > 0; off >>= 1) a += __shfl_down(a, off);
      if ((tid & 63) == 0) red[r][o][tid >> 6] = a;
    }
  __syncthreads();
  if (tid < kROWS * 2) {
    const int r = tid >> 1, o = tid & 1;
    part[(size_t)h * kB * 4 + (size_t)(b0 + r) * 4 + 2 + o] =
        red[r][o][0] + red[r][o][1] + red[r][o][2] + red[r][o][3];
  }
}

// ------------- short branch half: conv(k=3,p=1) -> relu -> partial dot -------------
__device__ __forceinline__ void short_half(
    int blk, int h, const float* __restrict__ xs, const float* __restrict__ cw,
    const float* __restrict__ cb, const float* __restrict__ lw,
    float* __restrict__ part) {
  __shared__ float red[kROWS][2][4];
  const int tid = threadIdx.x;
  const int b0 = blk * kROWS;

  float wgt[8][3], bias[8];
#pragma unroll
  for (int c = 0; c < 8; ++c) {
#pragma unroll
    for (int k = 0; k < 3; ++k) wgt[c][k] = cw[c * 3 + k];
    bias[c] = cb[c];
  }

  float acc[kROWS][2];
#pragma unroll
  for (int r = 0; r < kROWS; ++r) { acc[r][0] = 0.f; acc[r][1] = 0.f; }

  {
    const int p0 = h * 1024 + tid * 4;  // position base (mult of 4)

    // ---- issue ALL loads first ----
    float w[kROWS][6];  // x[p0-1 .. p0+4]
#pragma unroll
    for (int r = 0; r < kROWS; ++r) {
      const float* x = xs + (size_t)(b0 + r) * kSW;
      float xm = (p0 > 0) ? x[p0 - 1] : 0.f;
      float4 f0 = *reinterpret_cast<const float4*>(x + p0);
      float xp = (p0 + 4 < kSW) ? x[p0 + 4] : 0.f;
      w[r][0] = xm;
      w[r][1] = f0.x; w[r][2] = f0.y; w[r][3] = f0.z; w[r][4] = f0.w;
      w[r][5] = xp;
    }
    float4 la4[8], lb4[8];
#pragma unroll
    for (int c = 0; c < 8; ++c) {
      la4[c] = *reinterpret_cast<const float4*>(lw + (size_t)c * kSW + p0);
      lb4[c] = *reinterpret_cast<const float4*>(lw + (size_t)(8 + c) * kSW + p0);
    }

    // ---- FMA burn ----
#pragma unroll
    for (int c = 0; c < 8; ++c) {
      const float la[4] = {la4[c].x, la4[c].y, la4[c].z, la4[c].w};
      const float lbv[4] = {lb4[c].x, lb4[c].y, lb4[c].z, lb4[c].w};
#pragma unroll
      for (int r = 0; r < kROWS; ++r) {
#pragma unroll
        for (int u = 0; u < 4; ++u) {
          float v = fmaf(wgt[c][0], w[r][u],
                    fmaf(wgt[c][1], w[r][u + 1],
                    fmaf(wgt[c][2], w[r][u + 2], bias[c])));
          const float m = fmaxf(v, 0.f);
          acc[r][0] = fmaf(m, la[u], acc[r][0]);
          acc[r][1] = fmaf(m, lbv[u], acc[r][1]);
        }
      }
    }
  }

#pragma unroll
  for (int r = 0; r < kROWS; ++r)
#pragma unroll
    for (int o = 0; o < 2; ++o) {
      float a = acc[r][o];
#pragma unroll
      for (int off = 32; off > 0; off >>= 1) a += __shfl_down(a, off);
      if ((tid & 63) == 0) red[r][o][tid >> 6] = a;
    }
  __syncthreads();
  if (tid < kROWS * 2) {
    const int r = tid >> 1, o = tid & 1;
    part[(size_t)h * kB * 4 + (size_t)(b0 + r) * 4 + o] =
        red[r][o][0] + red[r][o][1] + red[r][o][2] + red[r][o][3];
  }
}

// ------------- fused feature kernel: long blocks first, short blocks after -------------
__global__ __launch_bounds__(256, 3) void features_kernel(
    const float* __restrict__ xs, const float* __restrict__ cs_cw,
    const float* __restrict__ cs_cb, const float* __restrict__ cs_lw,
    const float* __restrict__ xl, const float* __restrict__ cl_cw,
    const float* __restrict__ cl_cb, const float* __restrict__ cl_lw,
    float* __restrict__ part) {
  const int bid = blockIdx.x;
  if (bid < kLBLKS)
    long_half(bid >> 1, bid & 1, xl, cl_cw, cl_cb, cl_lw, part);
  else {
    const int s = bid - kLBLKS;
    short_half(s >> 1, s & 1, xs, cs_cw, cs_cb, cs_lw, part);
  }
}

// ---------------- 4-qubit statevector circuit + final linear ----------------
template <int MASK>
__device__ __forceinline__ void apply_1q(float (&ar)[16], float (&ai)[16],
                                         float u00r, float u00i, float u01r, float u01i,
                                         float u10r, float u10i, float u11r, float u11i) {
#pragma unroll
  for (int i = 0; i < 16; ++i) {
    if (!(i & MASK)) {
      const int j = i | MASK;
      const float a0r = ar[i], a0i = ai[i];
      const float a1r = ar[j], a1i = ai[j];
      ar[i] = u00r * a0r - u00i * a0i + u01r * a1r - u01i * a1i;
      ai[i] = u00r * a0i + u00i * a0r + u01r * a1i + u01i * a1r;
      ar[j] = u10r * a0r - u10i * a0i + u11r * a1r - u11i * a1i;
      ai[j] = u10r * a0i + u10i * a0r + u11r * a1i + u11i * a1r;
    }
  }
}

template <int MASK>
__device__ __forceinline__ void apply_ry(float (&ar)[16], float (&ai)[16], float half_t) {
  float s, c;
  sincosf(half_t, &s, &c);
  apply_1q<MASK>(ar, ai, c, 0.f, -s, 0.f, s, 0.f, c, 0.f);
}

// Rot(phi, theta, omega) = RZ(omega) @ RY(theta) @ RZ(phi)
template <int MASK>
__device__ __forceinline__ void apply_rot(float (&ar)[16], float (&ai)[16],
                                          float phi, float theta, float omega) {
  float st, ct; sincosf(0.5f * theta, &st, &ct);
  float sa, ca; sincosf(0.5f * (phi + omega), &sa, &ca);
  float sm, cm; sincosf(0.5f * (phi - omega), &sm, &cm);
  apply_1q<MASK>(ar, ai,
                 ct * ca, -ct * sa,
                 -st * cm, -st * sm,
                 st * cm, -st * sm,
                 ct * ca, ct * sa);
}

template <int MC, int MT>
__device__ __forceinline__ void apply_cnot(float (&ar)[16], float (&ai)[16]) {
#pragma unroll
  for (int i = 0; i < 16; ++i) {
    if ((i & MC) && !(i & MT)) {
      const int j = i | MT;
      float t;
      t = ar[i]; ar[i] = ar[j]; ar[j] = t;
      t = ai[i]; ai[i] = ai[j]; ai[j] = t;
    }
  }
}

__global__ __launch_bounds__(64) void quantum_kernel(
    const float* __restrict__ part, const float* __restrict__ cs_lb,
    const float* __restrict__ cl_lb, const float* __restrict__ rw,
    const float* __restrict__ fcw, const float* __restrict__ fcb,
    float* __restrict__ out) {
  const int b = blockIdx.x * 64 + threadIdx.x;
  if (b >= kB) return;

  const float f0 = part[(size_t)b * 4 + 0] + part[(size_t)kB * 4 + b * 4 + 0] + cs_lb[0];
  const float f1 = part[(size_t)b * 4 + 1] + part[(size_t)kB * 4 + b * 4 + 1] + cs_lb[1];
  const float f2 = part[(size_t)b * 4 + 2] + part[(size_t)kB * 4 + b * 4 + 2] + cl_lb[0];
  const float f3 = part[(size_t)b * 4 + 3] + part[(size_t)kB * 4 + b * 4 + 3] + cl_lb[1];

  float ar[16], ai[16];
#pragma unroll
  for (int i = 0; i < 16; ++i) { ar[i] = 0.f; ai[i] = 0.f; }
  ar[0] = 1.f;

  const float kHalfPi = 1.57079632679489662f;
  apply_ry<8>(ar, ai, kHalfPi * f0);
  apply_ry<4>(ar, ai, kHalfPi * f1);
  apply_ry<2>(ar, ai, kHalfPi * f2);
  apply_ry<1>(ar, ai, kHalfPi * f3);

  // layer 0, r = 1
  apply_rot<8>(ar, ai, rw[0], rw[1], rw[2]);
  apply_rot<4>(ar, ai, rw[3], rw[4], rw[5]);
  apply_rot<2>(ar, ai, rw[6], rw[7], rw[8]);
  apply_rot<1>(ar, ai, rw[9], rw[10], rw[11]);
  apply_cnot<8, 4>(ar, ai);
  apply_cnot<4, 2>(ar, ai);
  apply_cnot<2, 1>(ar, ai);
  apply_cnot<1, 8>(ar, ai);

  // layer 1, r = 2
  apply_rot<8>(ar, ai, rw[12], rw[13], rw[14]);
  apply_rot<4>(ar, ai, rw[15], rw[16], rw[17]);
  apply_rot<2>(ar, ai, rw[18], rw[19], rw[20]);
  apply_rot<1>(ar, ai, rw[21], rw[22], rw[23]);
  apply_cnot<8, 2>(ar, ai);
  apply_cnot<4, 1>(ar, ai);
  apply_cnot<2, 8>(ar, ai);
  apply_cnot<1, 4>(ar, ai);

  // layer 2, r = 3
  apply_rot<8>(ar, ai, rw[24], rw[25], rw[26]);
  apply_rot<4>(ar, ai, rw[27], rw[28], rw[29]);
  apply_rot<2>(ar, ai, rw[30], rw[31], rw[32]);
  apply_rot<1>(ar, ai, rw[33], rw[34], rw[35]);
  apply_cnot<8, 1>(ar, ai);
  apply_cnot<4, 8>(ar, ai);
  apply_cnot<2, 4>(ar, ai);
  apply_cnot<1, 2>(ar, ai);

  float z0 = 0.f, z1 = 0.f, z2 = 0.f, z3 = 0.f;
#pragma unroll
  for (int i = 0; i < 16; ++i) {
    const float p = ar[i] * ar[i] + ai[i] * ai[i];
    z0 += (i & 8) ? -p : p;
    z1 += (i & 4) ? -p : p;
    z2 += (i & 2) ? -p : p;
    z3 += (i & 1) ? -p : p;
  }
  out[b] = fcb[0] + z0 * fcw[0] + z1 * fcw[1] + z2 * fcw[2] + z3 * fcw[3];
}

extern "C" void kernel_launch(void* const* d_in, const int* in_sizes, int n_in,
                              void* d_out, int out_size, void* d_ws, size_t ws_size,
                              hipStream_t stream) {
  const float* xs     = (const float*)d_in[0];
  const float* xl     = (const float*)d_in[1];
  const float* cs_cw  = (const float*)d_in[2];
  const float* cs_cb  = (const float*)d_in[3];
  const float* cs_lw  = (const float*)d_in[4];
  const float* cs_lb  = (const float*)d_in[5];
  const float* cl_cw  = (const float*)d_in[6];
  const float* cl_cb  = (const float*)d_in[7];
  const float* cl_lw  = (const float*)d_in[8];
  const float* cl_lb  = (const float*)d_in[9];
  const float* rw     = (const float*)d_in[10];
  const float* fcw    = (const float*)d_in[11];
  const float* fcb    = (const float*)d_in[12];
  float* out  = (float*)d_out;
  float* part = (float*)d_ws;  // [2][kB][4] partial features

  hipLaunchKernelGGL(features_kernel, dim3(kLBLKS + kSBLKS), dim3(256), 0, stream,
                     xs, cs_cw, cs_cb, cs_lw,
                     xl, cl_cw, cl_cb, cl_lw, part);
  hipLaunchKernelGGL(quantum_kernel, dim3(kB / 64), dim3(64), 0, stream,
                     part, cs_lb, cl_lb, rw, fcw, fcb, out);
}